// Round 3
// baseline (1357.027 us; speedup 1.0000x reference)
//
#include <hip/hip_runtime.h>

typedef unsigned short u16;

// ---------- bf16 helpers ----------
__device__ __forceinline__ float bf2f(u16 v) {
  return __uint_as_float(((unsigned int)v) << 16);
}
__device__ __forceinline__ u16 f2bf(float f) {
  unsigned int u = __float_as_uint(f);
  unsigned int r = u + 0x7FFFu + ((u >> 16) & 1u);  // RNE
  return (u16)(r >> 16);
}
__device__ __forceinline__ float bflo(unsigned int w) { return __uint_as_float(w << 16); }
__device__ __forceinline__ float bfhi(unsigned int w) { return __uint_as_float(w & 0xFFFF0000u); }

// flagged 8-wide load (isf32 is wave-uniform): isf32=1 -> f32, 0 -> bf16
__device__ __forceinline__ void load8(const void* base, size_t off, int isf32, float v[8]) {
  if (isf32) {
    const float* p = (const float*)base + off;
    float4 a = *(const float4*)p, b = *(const float4*)(p + 4);
    v[0]=a.x; v[1]=a.y; v[2]=a.z; v[3]=a.w; v[4]=b.x; v[5]=b.y; v[6]=b.z; v[7]=b.w;
  } else {
    uint4 r = *(const uint4*)((const u16*)base + off);
    v[0]=bflo(r.x); v[1]=bfhi(r.x); v[2]=bflo(r.y); v[3]=bfhi(r.y);
    v[4]=bflo(r.z); v[5]=bfhi(r.z); v[6]=bflo(r.w); v[7]=bfhi(r.w);
  }
}
__device__ __forceinline__ float ldf1(const void* p, size_t i, int isf32) {
  return isf32 ? ((const float*)p)[i] : bf2f(((const u16*)p)[i]);
}
__device__ __forceinline__ uint4 pack8(const float v[8]) {
  uint4 o;
  o.x = (unsigned int)f2bf(v[0]) | ((unsigned int)f2bf(v[1]) << 16);
  o.y = (unsigned int)f2bf(v[2]) | ((unsigned int)f2bf(v[3]) << 16);
  o.z = (unsigned int)f2bf(v[4]) | ((unsigned int)f2bf(v[5]) << 16);
  o.w = (unsigned int)f2bf(v[6]) | ((unsigned int)f2bf(v[7]) << 16);
  return o;
}

// ---------- sizes ----------
#define LQ   2500
#define BB   2
#define CC   256
#define DH   32
#define NCC  6
#define HFF  64
#define WFF  176
#define DFF  1024
#define MROWS 5000  // LQ*BB

// ---------- workspace layout (BYTE offsets, total ~19.8 MB) ----------
// flag @0 | UV(f32,60032) @256 | A,B,C,D (u16, 1.28M each) | H (u16, 5.12M)
#define WB_UV   256
#define WB_A    240384
#define WB_B    (WB_A + 2560000)
#define WB_C    (WB_B + 2560000)
#define WB_D    (WB_C + 2560000)
#define WB_H    (WB_D + 2560000)
// end = WB_H + 10240000 = 20,720,384 bytes

// ============================================================
// dtype detection: scan reference_points as bf16 u16s.
// ============================================================
__global__ void detect_k(const u16* __restrict__ rp, int* __restrict__ flag) {
  int bad = 0;
  for (int i = threadIdx.x; i < 7500; i += 64) {
    float v = bf2f(rp[i]);
    if (!(fabsf(v) < 1e6f)) bad = 1;  // catches random-exponent garbage / NaN / Inf
  }
  int anybad = __any(bad);
  if (threadIdx.x == 0) flag[0] = anybad ? 1 : 0;   // 1 = f32, 0 = bf16
}

// ============================================================
// Generic tiled GEMM: Y(M,N) = act(X @ W' + bias) [+ res], Y stored bf16 ws.
// XRAW: X is flagged raw input (else bf16 ws). WTR=1: W stored (N,K).
// W/bias are flagged raw inputs (element offsets woff/boff applied at runtime).
// RES: 0 none, 1 bf16 ws, 2 flagged raw. ACT: exact gelu.
// ============================================================
template<int XRAW, int WTR, int ACT, int RES>
__global__ __launch_bounds__(256) void gemm_k(
    const void* __restrict__ Xv, const void* __restrict__ W, size_t woff,
    const void* __restrict__ bias, size_t boff, const void* __restrict__ resv,
    u16* __restrict__ Y, int M, int N, int K, const int* __restrict__ flag)
{
  const int df = flag[0];
  __shared__ float As[16][132];
  __shared__ float Bs[16][132];
  const int t = threadIdx.x;
  const int m0 = blockIdx.y * 128, n0 = blockIdx.x * 128;
  float acc[8][8];
#pragma unroll
  for (int r = 0; r < 8; ++r)
#pragma unroll
    for (int c = 0; c < 8; ++c) acc[r][c] = 0.f;

  const int arow = t >> 1, akk = (t & 1) * 8;
  const int mb = (t >> 4) * 8, nb = (t & 15) * 8;

  for (int k0 = 0; k0 < K; k0 += 16) {
    {  // A tile: As[k][m]
      const int gm = m0 + arow;
      float av[8] = {0.f,0.f,0.f,0.f,0.f,0.f,0.f,0.f};
      if (gm < M) load8(Xv, (size_t)gm * K + k0 + akk, XRAW ? df : 0, av);
#pragma unroll
      for (int i = 0; i < 8; ++i) As[akk + i][arow] = av[i];
    }
    // B tile: Bs[k][n]
    if (WTR) {
      const int bn = t >> 1, bkk = (t & 1) * 8;
      float bv[8];
      load8(W, woff + (size_t)(n0 + bn) * K + k0 + bkk, df, bv);
#pragma unroll
      for (int x = 0; x < 8; ++x) Bs[bkk + x][bn] = bv[x];
    } else {
      const int bk = t >> 4, bnn = (t & 15) * 8;
      float bv[8];
      load8(W, woff + (size_t)(k0 + bk) * N + n0 + bnn, df, bv);
#pragma unroll
      for (int x = 0; x < 8; ++x) Bs[bk][bnn + x] = bv[x];
    }
    __syncthreads();
#pragma unroll
    for (int k = 0; k < 16; ++k) {
      float4 a0 = *(const float4*)&As[k][mb];
      float4 a1 = *(const float4*)&As[k][mb + 4];
      float4 b0 = *(const float4*)&Bs[k][nb];
      float4 b1 = *(const float4*)&Bs[k][nb + 4];
      float aa[8] = {a0.x,a0.y,a0.z,a0.w,a1.x,a1.y,a1.z,a1.w};
      float bb[8] = {b0.x,b0.y,b0.z,b0.w,b1.x,b1.y,b1.z,b1.w};
#pragma unroll
      for (int r = 0; r < 8; ++r)
#pragma unroll
        for (int c = 0; c < 8; ++c) acc[r][c] = fmaf(aa[r], bb[c], acc[r][c]);
    }
    __syncthreads();
  }
  // epilogue
  float bv[8];
#pragma unroll
  for (int c = 0; c < 8; ++c) bv[c] = ldf1(bias, boff + n0 + nb + c, df);
#pragma unroll
  for (int r = 0; r < 8; ++r) {
    const int gm = m0 + mb + r;
    if (gm >= M) continue;
    float v[8];
#pragma unroll
    for (int c = 0; c < 8; ++c) {
      float x = acc[r][c] + bv[c];
      if (ACT) x = 0.5f * x * (1.f + erff(x * 0.70710678118654752f));
      v[c] = x;
    }
    if (RES == 1) {
      float rv[8];
      load8(resv, (size_t)gm * N + n0 + nb, 0, rv);
#pragma unroll
      for (int c = 0; c < 8; ++c) v[c] += rv[c];
    } else if (RES == 2) {
      float rv[8];
      load8(resv, (size_t)gm * N + n0 + nb, df, rv);
#pragma unroll
      for (int c = 0; c < 8; ++c) v[c] += rv[c];
    }
    *(uint4*)(Y + (size_t)gm * N + n0 + nb) = pack8(v);
  }
}

// ============================================================
// Flash attention: 64-query tile per block, one (b,h) per blockIdx.y.
// Q/K/V/O are bf16 ws, layout row=(l*B+b), col=h*32+d. Online softmax.
// ============================================================
__global__ __launch_bounds__(256) void attn_k(
    const u16* __restrict__ Qw, const u16* __restrict__ Kw,
    const u16* __restrict__ Vw, u16* __restrict__ Ow)
{
  __shared__ float sQT[32][68];
  __shared__ float sKT[32][68];
  __shared__ float sVT[32][68];
  __shared__ float sS[64][68];
  __shared__ float sm[64], sl[64], sal[64];
  const int t = threadIdx.x;
  const int q0 = blockIdx.x * 64;
  const int b = blockIdx.y >> 3, h = blockIdx.y & 7;

  {  // Q load (transposed, pre-scaled)
    const int i = t >> 2, d0 = (t & 3) * 8;
    const int q = q0 + i;
    float v[8] = {0.f,0.f,0.f,0.f,0.f,0.f,0.f,0.f};
    if (q < LQ) load8(Qw, ((size_t)q * BB + b) * CC + h * DH + d0, 0, v);
    const float sc = 0.17677669529663687f;
#pragma unroll
    for (int x = 0; x < 8; ++x) sQT[d0 + x][i] = v[x] * sc;
  }
  if (t < 64) { sm[t] = -1e30f; sl[t] = 0.f; }
  float acc[4][2] = {{0.f,0.f},{0.f,0.f},{0.f,0.f},{0.f,0.f}};
  const int i0 = (t >> 4) * 4;
  const int j0 = (t & 15) * 4;
  const int d0p = (t & 15) * 2;

  for (int kt = 0; kt < 40; ++kt) {
    const int kbase = kt * 64;
    int nk = LQ - kbase; if (nk > 64) nk = 64;
    {  // stage K,V (transposed)
      const int j = t >> 2, dd0 = (t & 3) * 8;
      const int jg = kbase + j;
      float kv[8] = {0.f,0.f,0.f,0.f,0.f,0.f,0.f,0.f};
      float vv[8] = {0.f,0.f,0.f,0.f,0.f,0.f,0.f,0.f};
      if (jg < LQ) {
        load8(Kw, ((size_t)jg * BB + b) * CC + h * DH + dd0, 0, kv);
        load8(Vw, ((size_t)jg * BB + b) * CC + h * DH + dd0, 0, vv);
      }
#pragma unroll
      for (int x = 0; x < 8; ++x) { sKT[dd0 + x][j] = kv[x]; sVT[dd0 + x][j] = vv[x]; }
    }
    __syncthreads();
    float s[4][4] = {{0.f,0.f,0.f,0.f},{0.f,0.f,0.f,0.f},{0.f,0.f,0.f,0.f},{0.f,0.f,0.f,0.f}};
#pragma unroll
    for (int d = 0; d < 32; ++d) {
      float4 qv = *(const float4*)&sQT[d][i0];
      float4 kv = *(const float4*)&sKT[d][j0];
      float qa[4] = {qv.x,qv.y,qv.z,qv.w};
      float ka[4] = {kv.x,kv.y,kv.z,kv.w};
#pragma unroll
      for (int r = 0; r < 4; ++r)
#pragma unroll
        for (int c = 0; c < 4; ++c) s[r][c] = fmaf(qa[r], ka[c], s[r][c]);
    }
#pragma unroll
    for (int r = 0; r < 4; ++r) {
      float4 w;
      w.x = (j0 + 0 < nk) ? s[r][0] : -1e30f;
      w.y = (j0 + 1 < nk) ? s[r][1] : -1e30f;
      w.z = (j0 + 2 < nk) ? s[r][2] : -1e30f;
      w.w = (j0 + 3 < nk) ? s[r][3] : -1e30f;
      *(float4*)&sS[i0 + r][j0] = w;
    }
    __syncthreads();
    {  // online softmax: 4 lanes per row
      const int r = t >> 2;
      const int g = t & 3;
      float* rowp = &sS[r][g * 16];
      float sv[16];
      float4 x0 = *(const float4*)(rowp + 0), x1 = *(const float4*)(rowp + 4);
      float4 x2 = *(const float4*)(rowp + 8), x3 = *(const float4*)(rowp + 12);
      sv[0]=x0.x; sv[1]=x0.y; sv[2]=x0.z; sv[3]=x0.w;
      sv[4]=x1.x; sv[5]=x1.y; sv[6]=x1.z; sv[7]=x1.w;
      sv[8]=x2.x; sv[9]=x2.y; sv[10]=x2.z; sv[11]=x2.w;
      sv[12]=x3.x; sv[13]=x3.y; sv[14]=x3.z; sv[15]=x3.w;
      float mloc = sv[0];
#pragma unroll
      for (int jj = 1; jj < 16; ++jj) mloc = fmaxf(mloc, sv[jj]);
      mloc = fmaxf(mloc, __shfl_xor(mloc, 1));
      mloc = fmaxf(mloc, __shfl_xor(mloc, 2));
      const float mold = sm[r];
      const float mnew = fmaxf(mold, mloc);
      float ssum = 0.f;
#pragma unroll
      for (int jj = 0; jj < 16; ++jj) { float e = __expf(sv[jj] - mnew); sv[jj] = e; ssum += e; }
      *(float4*)(rowp + 0)  = make_float4(sv[0],sv[1],sv[2],sv[3]);
      *(float4*)(rowp + 4)  = make_float4(sv[4],sv[5],sv[6],sv[7]);
      *(float4*)(rowp + 8)  = make_float4(sv[8],sv[9],sv[10],sv[11]);
      *(float4*)(rowp + 12) = make_float4(sv[12],sv[13],sv[14],sv[15]);
      ssum += __shfl_xor(ssum, 1);
      ssum += __shfl_xor(ssum, 2);
      if (g == 0) {
        float al = __expf(mold - mnew);
        sl[r] = sl[r] * al + ssum;
        sm[r] = mnew;
        sal[r] = al;
      }
    }
    __syncthreads();
    {  // rescale + P·V
      float al[4];
#pragma unroll
      for (int r = 0; r < 4; ++r) al[r] = sal[i0 + r];
#pragma unroll
      for (int r = 0; r < 4; ++r) { acc[r][0] *= al[r]; acc[r][1] *= al[r]; }
#pragma unroll
      for (int j4 = 0; j4 < 64; j4 += 4) {
        float4 va = *(const float4*)&sVT[d0p][j4];
        float4 vb = *(const float4*)&sVT[d0p + 1][j4];
#pragma unroll
        for (int r = 0; r < 4; ++r) {
          float4 pv = *(const float4*)&sS[i0 + r][j4];
          acc[r][0] += pv.x*va.x + pv.y*va.y + pv.z*va.z + pv.w*va.w;
          acc[r][1] += pv.x*vb.x + pv.y*vb.y + pv.z*vb.z + pv.w*vb.w;
        }
      }
    }
    __syncthreads();
  }
#pragma unroll
  for (int r = 0; r < 4; ++r) {
    const int q = q0 + i0 + r;
    if (q < LQ) {
      const float inv = 1.0f / sl[i0 + r];
      u16* p = Ow + ((size_t)q * BB + b) * CC + h * DH + d0p;
      unsigned int w = (unsigned int)f2bf(acc[r][0] * inv) |
                       ((unsigned int)f2bf(acc[r][1] * inv) << 16);
      *(unsigned int*)p = w;
    }
  }
}

// ============================================================
// LayerNorm over C=256; one wave per row; 4 rows per block.
// X bf16 ws. g/b flagged raw. TOOUT=1: store d_out in flagged dtype, else bf16 ws.
// ============================================================
template<int TOOUT>
__global__ __launch_bounds__(256) void ln_k(const u16* __restrict__ X,
    const void* __restrict__ g, const void* __restrict__ be,
    void* __restrict__ Yv, int rows, const int* __restrict__ flag)
{
  const int df = flag[0];
  const int lane = threadIdx.x & 63;
  const int row = blockIdx.x * 4 + (threadIdx.x >> 6);
  if (row >= rows) return;
  uint2 raw = *(const uint2*)(X + (size_t)row * CC + lane * 4);
  float vx = bflo(raw.x), vy = bfhi(raw.x), vz = bflo(raw.y), vw = bfhi(raw.y);
  float s = vx + vy + vz + vw;
#pragma unroll
  for (int o = 1; o < 64; o <<= 1) s += __shfl_xor(s, o);
  const float mean = s * 0.00390625f;
  const float dx = vx - mean, dy = vy - mean, dz = vz - mean, dw = vw - mean;
  float sq = dx*dx + dy*dy + dz*dz + dw*dw;
#pragma unroll
  for (int o = 1; o < 64; o <<= 1) sq += __shfl_xor(sq, o);
  const float rstd = rsqrtf(sq * 0.00390625f + 1e-5f);
  const float g0 = ldf1(g, lane*4+0, df), g1 = ldf1(g, lane*4+1, df);
  const float g2 = ldf1(g, lane*4+2, df), g3 = ldf1(g, lane*4+3, df);
  const float b0 = ldf1(be, lane*4+0, df), b1 = ldf1(be, lane*4+1, df);
  const float b2 = ldf1(be, lane*4+2, df), b3 = ldf1(be, lane*4+3, df);
  const float y0 = dx * rstd * g0 + b0;
  const float y1 = dy * rstd * g1 + b1;
  const float y2 = dz * rstd * g2 + b2;
  const float y3 = dw * rstd * g3 + b3;
  if (TOOUT && df) {
    float* yp = (float*)Yv + (size_t)row * CC + lane * 4;
    *(float4*)yp = make_float4(y0, y1, y2, y3);
  } else {
    u16* yp = (u16*)Yv + (size_t)row * CC + lane * 4;
    unsigned int lo = (unsigned int)f2bf(y0) | ((unsigned int)f2bf(y1) << 16);
    unsigned int hi = (unsigned int)f2bf(y2) | ((unsigned int)f2bf(y3) << 16);
    *(uint2*)yp = make_uint2(lo, hi);
  }
}

// ============================================================
// Camera projection (flagged raw params)
// ============================================================
__global__ __launch_bounds__(256) void uv_k(
    const void* __restrict__ refp, const void* __restrict__ intr,
    const void* __restrict__ extr, float* __restrict__ uv,
    const int* __restrict__ flag)
{
  const int df = flag[0];
  const int idx = blockIdx.x * 256 + threadIdx.x;
  if (idx >= BB * NCC * LQ) return;
  const int bc = idx / LQ;
  const int q = idx - bc * LQ;
  float R[3][3], tv[3], Kc[3][3], p[3];
#pragma unroll
  for (int i = 0; i < 3; ++i) {
#pragma unroll
    for (int j = 0; j < 3; ++j) {
      R[i][j] = ldf1(extr, bc*16 + i*4 + j, df);
      Kc[i][j] = ldf1(intr, bc*9 + i*3 + j, df);
    }
    tv[i] = ldf1(extr, bc*16 + i*4 + 3, df);
  }
#pragma unroll
  for (int j = 0; j < 3; ++j) p[j] = ldf1(refp, q*3 + j, df) - tv[j];
  float pc[3];
#pragma unroll
  for (int i = 0; i < 3; ++i) pc[i] = R[0][i]*p[0] + R[1][i]*p[1] + R[2][i]*p[2];
  float im[3];
#pragma unroll
  for (int i = 0; i < 3; ++i) im[i] = Kc[i][0]*pc[0] + Kc[i][1]*pc[1] + Kc[i][2]*pc[2];
  const float z = fmaxf(im[2], 1e-5f);
  uv[(size_t)idx*2 + 0] = im[0] / z - 0.5f;
  uv[(size_t)idx*2 + 1] = im[1] / z - 0.5f;
}

// ============================================================
// Bilinear sampler, mean over cams. Block = one (c, b); threads stride q.
// Output bf16 ws (scalar u16 stores).
// ============================================================
__global__ __launch_bounds__(256) void samp_k(
    const void* __restrict__ feat, const float* __restrict__ uv,
    u16* __restrict__ S, const int* __restrict__ flag)
{
  const int df = flag[0];
  const int c = blockIdx.x;
  const int b = blockIdx.y;
  for (int q = threadIdx.x; q < LQ; q += 256) {
    float acc = 0.f;
#pragma unroll
    for (int cam = 0; cam < NCC; ++cam) {
      const int bc = b * NCC + cam;
      const float x = uv[((size_t)bc * LQ + q) * 2 + 0];
      const float y = uv[((size_t)bc * LQ + q) * 2 + 1];
      const float xf = floorf(x), yf = floorf(y);
      const int x0 = (int)xf, y0 = (int)yf;
      const float wx = x - xf, wy = y - yf;
      const size_t base = ((size_t)bc * CC + c) * (HFF * WFF);
      const bool vx0 = (x0 >= 0) & (x0 < WFF);
      const bool vx1 = (x0 + 1 >= 0) & (x0 + 1 < WFF);
      const bool vy0 = (y0 >= 0) & (y0 < HFF);
      const bool vy1 = (y0 + 1 >= 0) & (y0 + 1 < HFF);
      if (vy0) {
        const size_t rb = base + (size_t)y0 * WFF;
        if (vx0) acc += (1.f - wx) * (1.f - wy) * ldf1(feat, rb + x0, df);
        if (vx1) acc += wx * (1.f - wy) * ldf1(feat, rb + x0 + 1, df);
      }
      if (vy1) {
        const size_t rb = base + (size_t)(y0 + 1) * WFF;
        if (vx0) acc += (1.f - wx) * wy * ldf1(feat, rb + x0, df);
        if (vx1) acc += wx * wy * ldf1(feat, rb + x0 + 1, df);
      }
    }
    S[((size_t)q * BB + b) * CC + c] = f2bf(acc * (1.f / 6.f));
  }
}

// ============================================================
extern "C" void kernel_launch(void* const* d_in, const int* in_sizes, int n_in,
                              void* d_out, int out_size, void* d_ws, size_t ws_size,
                              hipStream_t stream) {
  (void)in_sizes; (void)n_in; (void)out_size; (void)ws_size;
  char* base = (char*)d_ws;
  int* flag = (int*)base;
  float* UV = (float*)(base + WB_UV);
  u16* A = (u16*)(base + WB_A);
  u16* B = (u16*)(base + WB_B);
  u16* C = (u16*)(base + WB_C);
  u16* D = (u16*)(base + WB_D);
  u16* H = (u16*)(base + WB_H);

  // dtype detection (reference_points = d_in[3])
  detect_k<<<1, 64, 0, stream>>>((const u16*)d_in[3], flag);

  // camera projection
  uv_k<<<(BB * NCC * LQ + 255) / 256, 256, 0, stream>>>(d_in[3], d_in[4], d_in[5], UV, flag);

  // TSA: Q/K/V projections (W = in_proj_w (3C,C) row-major, use W^T)
  gemm_k<1,1,0,0><<<dim3(2, 40), 256, 0, stream>>>(d_in[0], d_in[7], 0,        d_in[8], 0,   nullptr, A, MROWS, CC, CC, flag);
  gemm_k<1,1,0,0><<<dim3(2, 40), 256, 0, stream>>>(d_in[1], d_in[7], 65536,    d_in[8], 256, nullptr, B, MROWS, CC, CC, flag);
  gemm_k<1,1,0,0><<<dim3(2, 40), 256, 0, stream>>>(d_in[1], d_in[7], 131072,   d_in[8], 512, nullptr, C, MROWS, CC, CC, flag);

  attn_k<<<dim3(40, 16), 256, 0, stream>>>(A, B, C, D);

  // out-proj (+bevq residual, flagged raw) -> B, LN1 -> C
  gemm_k<0,1,0,2><<<dim3(2, 40), 256, 0, stream>>>(D, d_in[9], 0, d_in[10], 0, d_in[0], B, MROWS, CC, CC, flag);
  ln_k<0><<<1250, 256, 0, stream>>>(B, d_in[11], d_in[12], C, MROWS, flag);

  // sampling into A (Q slot now dead)
  samp_k<<<dim3(CC, BB), 256, 0, stream>>>(d_in[2], UV, A, flag);

  // SCA proj (+C residual) -> D, LN2 -> A
  gemm_k<0,1,0,1><<<dim3(2, 40), 256, 0, stream>>>(A, d_in[13], 0, d_in[14], 0, C, D, MROWS, CC, CC, flag);
  ln_k<0><<<1250, 256, 0, stream>>>(D, d_in[15], d_in[16], A, MROWS, flag);

  // FFN: gelu(A @ W1 + b1) -> H ; H @ W2 + b2 + A -> B ; LN3 -> d_out
  gemm_k<0,0,1,0><<<dim3(8, 40), 256, 0, stream>>>(A, d_in[17], 0, d_in[18], 0, nullptr, H, MROWS, DFF, CC, flag);
  gemm_k<0,0,0,1><<<dim3(2, 40), 256, 0, stream>>>(H, d_in[19], 0, d_in[20], 0, A, B, MROWS, CC, DFF, flag);
  ln_k<1><<<1250, 256, 0, stream>>>(B, d_in[21], d_in[22], d_out, MROWS, flag);
}

// Round 4
// 545.537 us; speedup vs baseline: 2.4875x; 2.4875x over previous
//
#include <hip/hip_runtime.h>

typedef unsigned short u16;
typedef __attribute__((ext_vector_type(8))) __bf16 bf8_t;
typedef __attribute__((ext_vector_type(4))) float f4_t;

// ---------- bf16 helpers ----------
__device__ __forceinline__ float bf2f(u16 v) {
  return __uint_as_float(((unsigned int)v) << 16);
}
__device__ __forceinline__ u16 f2bf(float f) {
  unsigned int u = __float_as_uint(f);
  unsigned int r = u + 0x7FFFu + ((u >> 16) & 1u);  // RNE
  return (u16)(r >> 16);
}
__device__ __forceinline__ float bflo(unsigned int w) { return __uint_as_float(w << 16); }
__device__ __forceinline__ float bfhi(unsigned int w) { return __uint_as_float(w & 0xFFFF0000u); }

__device__ __forceinline__ void load8(const void* base, size_t off, int isf32, float v[8]) {
  if (isf32) {
    const float* p = (const float*)base + off;
    float4 a = *(const float4*)p, b = *(const float4*)(p + 4);
    v[0]=a.x; v[1]=a.y; v[2]=a.z; v[3]=a.w; v[4]=b.x; v[5]=b.y; v[6]=b.z; v[7]=b.w;
  } else {
    uint4 r = *(const uint4*)((const u16*)base + off);
    v[0]=bflo(r.x); v[1]=bfhi(r.x); v[2]=bflo(r.y); v[3]=bfhi(r.y);
    v[4]=bflo(r.z); v[5]=bfhi(r.z); v[6]=bflo(r.w); v[7]=bfhi(r.w);
  }
}
__device__ __forceinline__ float ldf1(const void* p, size_t i, int isf32) {
  return isf32 ? ((const float*)p)[i] : bf2f(((const u16*)p)[i]);
}

// ---------- sizes ----------
#define LQ   2500
#define BB   2
#define CC   256
#define DH   32
#define NCC  6
#define HFF  64
#define WFF  176
#define DFF  1024
#define MROWS 5000

// ---------- workspace byte offsets (total 17,672,832 B) ----------
#define WB_UV   256
#define WB_WQKV 240256
#define WB_WOP  633472
#define WB_WSC  764544
#define WB_WF1  895616
#define WB_WF2  1419904
#define WB_S1   1944192
#define WB_S2   (WB_S1 + 2621440)
#define WB_S3   (WB_S2 + 2621440)
#define WB_S4   (WB_S3 + 2621440)
#define WB_H    WB_S2              /* overlaps S2..S4 (dead at FFN time) */
#define WB_Y3   (WB_S2 + 10485760)

// ============================================================
__global__ void detect_k(const u16* __restrict__ rp, int* __restrict__ flag) {
  int bad = 0;
  for (int i = threadIdx.x; i < 7500; i += 64) {
    float v = bf2f(rp[i]);
    if (!(fabsf(v) < 1e6f)) bad = 1;
  }
  int anybad = __any(bad);
  if (threadIdx.x == 0) flag[0] = anybad ? 1 : 0;   // 1 = f32, 0 = bf16
}

// ============================================================
// weight prep: convert (and transpose for FFN) into bf16 (N,K) ws
// ============================================================
struct WDesc {
  const void* src[5];
  u16* dst[5];
  int n[5];
  int mode[5];     // 0 direct, 1 transpose (src (Kd,Nd) -> dst (Nd,Kd))
  int Kd[5], Nd[5];
};
__global__ __launch_bounds__(256) void cvtw_k(WDesc d, const int* __restrict__ flag) {
  const int df = flag[0];
  const int i = blockIdx.y;
  const int n = d.n[i];
  for (int j = blockIdx.x * 256 + threadIdx.x; j < n; j += gridDim.x * 256) {
    float v;
    if (d.mode[i]) {
      const int K = d.Kd[i], N = d.Nd[i];
      const int nn = j / K, kk = j - nn * K;
      v = ldf1(d.src[i], (size_t)kk * N + nn, df);
    } else {
      v = ldf1(d.src[i], j, df);
    }
    d.dst[i][j] = f2bf(v);
  }
}

// ============================================================
// MFMA GEMM: Y(M,N) = act(X @ W^T + bias) [+ res], Y bf16 ws.
// W bf16 ws (N,K). XRAW: X flagged raw (else bf16 ws).
// RES: 0 none, 1 bf16 ws, 2 flagged raw. ACT: exact gelu.
// Tile 64x64, BK=32, 256 thr; wave (wr,wc) does 32x32 via 2x2 MFMA tiles.
// ============================================================
template<int XRAW, int ACT, int RES>
__global__ __launch_bounds__(256) void gemm_mf(
    const void* __restrict__ Xv, const u16* __restrict__ W,
    const void* __restrict__ bias, size_t boff,
    const void* __restrict__ resv,
    u16* __restrict__ Y, int M, int N, int K, const int* __restrict__ flag)
{
  const int df = flag[0];
  const int xf = XRAW ? df : 0;
  __shared__ __align__(16) u16 sA[64 * 32];
  __shared__ __align__(16) u16 sB[64 * 32];
  const int t = threadIdx.x;
  const int m0 = blockIdx.y * 64, n0 = blockIdx.x * 64;
  const int lane = t & 63, w = t >> 6;
  const int wr = w >> 1, wc = w & 1;
  const int ln15 = lane & 15, l4 = lane >> 4;

  f4_t acc[2][2];
#pragma unroll
  for (int a = 0; a < 2; ++a)
#pragma unroll
    for (int bq = 0; bq < 2; ++bq) acc[a][bq] = (f4_t){0.f, 0.f, 0.f, 0.f};

  const int srow = t >> 2, scol = (t & 3) * 8;
  for (int k0 = 0; k0 < K; k0 += 32) {
    {  // stage A (with M guard + bf16 conversion)
      const int gm = m0 + srow;
      float v[8] = {0.f,0.f,0.f,0.f,0.f,0.f,0.f,0.f};
      if (gm < M) load8(Xv, (size_t)gm * K + k0 + scol, xf, v);
      uint4 o;
      o.x = (unsigned int)f2bf(v[0]) | ((unsigned int)f2bf(v[1]) << 16);
      o.y = (unsigned int)f2bf(v[2]) | ((unsigned int)f2bf(v[3]) << 16);
      o.z = (unsigned int)f2bf(v[4]) | ((unsigned int)f2bf(v[5]) << 16);
      o.w = (unsigned int)f2bf(v[6]) | ((unsigned int)f2bf(v[7]) << 16);
      *(uint4*)&sA[srow * 32 + scol] = o;
    }
    // stage B (bf16 ws, direct copy)
    *(uint4*)&sB[srow * 32 + scol] =
        *(const uint4*)&W[(size_t)(n0 + srow) * K + k0 + scol];
    __syncthreads();
    bf8_t af[2], bf_[2];
    af[0]  = *(const bf8_t*)&sA[(wr * 32 + 0  + ln15) * 32 + l4 * 8];
    af[1]  = *(const bf8_t*)&sA[(wr * 32 + 16 + ln15) * 32 + l4 * 8];
    bf_[0] = *(const bf8_t*)&sB[(wc * 32 + 0  + ln15) * 32 + l4 * 8];
    bf_[1] = *(const bf8_t*)&sB[(wc * 32 + 16 + ln15) * 32 + l4 * 8];
#pragma unroll
    for (int mt = 0; mt < 2; ++mt)
#pragma unroll
      for (int nt = 0; nt < 2; ++nt)
        acc[mt][nt] = __builtin_amdgcn_mfma_f32_16x16x32_bf16(af[mt], bf_[nt], acc[mt][nt], 0, 0, 0);
    __syncthreads();
  }
  // epilogue: D row=(lane>>4)*4+reg, col=lane&15
#pragma unroll
  for (int nt = 0; nt < 2; ++nt) {
    const int gn = n0 + wc * 32 + nt * 16 + ln15;
    const float bv = ldf1(bias, boff + gn, df);
#pragma unroll
    for (int mt = 0; mt < 2; ++mt)
#pragma unroll
      for (int r = 0; r < 4; ++r) {
        const int gm = m0 + wr * 32 + mt * 16 + l4 * 4 + r;
        if (gm < M) {
          float x = acc[mt][nt][r] + bv;
          if (ACT) x = 0.5f * x * (1.f + erff(x * 0.70710678118654752f));
          if (RES == 1)      x += bf2f(((const u16*)resv)[(size_t)gm * N + gn]);
          else if (RES == 2) x += ldf1(resv, (size_t)gm * N + gn, df);
          Y[(size_t)gm * N + gn] = f2bf(x);
        }
      }
  }
}

// ============================================================
// MFMA flash attention: 64 q-rows/block, one (b,h) per blockIdx.y.
// Wave w owns q-strip [w*16,+16). Row softmax stats in registers.
// ============================================================
__global__ __launch_bounds__(256) void attn_mf(
    const u16* __restrict__ Qw, const u16* __restrict__ Kw,
    const u16* __restrict__ Vw, u16* __restrict__ Ow)
{
  __shared__ __align__(16) u16 sQ[64 * 32];
  __shared__ __align__(16) u16 sK[64 * 32];
  __shared__ __align__(16) u16 sVT[32 * 72];
  __shared__ __align__(16) u16 sP[64 * 72];
  const int t = threadIdx.x;
  const int q0 = blockIdx.x * 64;
  const int b = blockIdx.y >> 3, h = blockIdx.y & 7;
  const int lane = t & 63, w = t >> 6;
  const int ln15 = lane & 15, l4 = lane >> 4;
  const float SC = 0.17677669529663687f;

  {  // stage Q once (row-major [64][32]); rows < 5120 alloc, safe
    const int qi = t >> 2, dcol = (t & 3) * 8;
    const size_t src = ((size_t)(q0 + qi) * BB + b) * CC + h * DH + dcol;
    *(uint4*)&sQ[qi * 32 + dcol] = *(const uint4*)&Qw[src];
  }

  f4_t oacc[2];
  oacc[0] = (f4_t){0.f,0.f,0.f,0.f};
  oacc[1] = (f4_t){0.f,0.f,0.f,0.f};
  float m_r[4] = {-1e30f, -1e30f, -1e30f, -1e30f};
  float l_r[4] = {0.f, 0.f, 0.f, 0.f};
  __syncthreads();

  for (int kt = 0; kt < 40; ++kt) {
    const int kbase = kt * 64;
    {  // stage K (row-major) + V transposed [32][72]
      const int j = t >> 2, dcol = (t & 3) * 8;
      const size_t src = ((size_t)(kbase + j) * BB + b) * CC + h * DH + dcol;
      *(uint4*)&sK[j * 32 + dcol] = *(const uint4*)&Kw[src];
      uint4 vv = *(const uint4*)&Vw[src];
      u16 ve[8];
      ve[0] = (u16)(vv.x & 0xffff); ve[1] = (u16)(vv.x >> 16);
      ve[2] = (u16)(vv.y & 0xffff); ve[3] = (u16)(vv.y >> 16);
      ve[4] = (u16)(vv.z & 0xffff); ve[5] = (u16)(vv.z >> 16);
      ve[6] = (u16)(vv.w & 0xffff); ve[7] = (u16)(vv.w >> 16);
#pragma unroll
      for (int x = 0; x < 8; ++x) sVT[(dcol + x) * 72 + j] = ve[x];
    }
    __syncthreads();

    // ---- S = Q K^T : 4 MFMAs per wave ----
    bf8_t aq = *(const bf8_t*)&sQ[(w * 16 + ln15) * 32 + l4 * 8];
    f4_t sv[4];
#pragma unroll
    for (int nt = 0; nt < 4; ++nt) {
      bf8_t bk = *(const bf8_t*)&sK[(nt * 16 + ln15) * 32 + l4 * 8];
      f4_t z = (f4_t){0.f,0.f,0.f,0.f};
      sv[nt] = __builtin_amdgcn_mfma_f32_16x16x32_bf16(aq, bk, z, 0, 0, 0);
    }

    // ---- scale + mask + online softmax (row = (l4)*4+r, col = nt*16+ln15) ----
    float p[4][4];
#pragma unroll
    for (int nt = 0; nt < 4; ++nt) {
      const bool ok = (kbase + nt * 16 + ln15) < LQ;
#pragma unroll
      for (int r = 0; r < 4; ++r)
        p[nt][r] = ok ? sv[nt][r] * SC : -1e30f;
    }
#pragma unroll
    for (int r = 0; r < 4; ++r) {
      float mloc = fmaxf(fmaxf(p[0][r], p[1][r]), fmaxf(p[2][r], p[3][r]));
      mloc = fmaxf(mloc, __shfl_xor(mloc, 1));
      mloc = fmaxf(mloc, __shfl_xor(mloc, 2));
      mloc = fmaxf(mloc, __shfl_xor(mloc, 4));
      mloc = fmaxf(mloc, __shfl_xor(mloc, 8));
      const float mn = fmaxf(m_r[r], mloc);
      const float alpha = __expf(m_r[r] - mn);
      m_r[r] = mn;
      float s = 0.f;
#pragma unroll
      for (int nt = 0; nt < 4; ++nt) { const float e = __expf(p[nt][r] - mn); p[nt][r] = e; s += e; }
      s += __shfl_xor(s, 1);
      s += __shfl_xor(s, 2);
      s += __shfl_xor(s, 4);
      s += __shfl_xor(s, 8);
      l_r[r] = l_r[r] * alpha + s;
      oacc[0][r] *= alpha;
      oacc[1][r] *= alpha;
    }

    // ---- P -> LDS (C/D layout -> A-operand layout round-trip, wave-private) ----
#pragma unroll
    for (int nt = 0; nt < 4; ++nt)
#pragma unroll
      for (int r = 0; r < 4; ++r)
        sP[(w * 16 + l4 * 4 + r) * 72 + nt * 16 + ln15] = f2bf(p[nt][r]);

    // ---- O += P V : 4 MFMAs per wave (no barrier: same-wave LDS in-order) ----
#pragma unroll
    for (int ks = 0; ks < 2; ++ks) {
      bf8_t ap = *(const bf8_t*)&sP[(w * 16 + ln15) * 72 + ks * 32 + l4 * 8];
#pragma unroll
      for (int nt = 0; nt < 2; ++nt) {
        bf8_t bv = *(const bf8_t*)&sVT[(nt * 16 + ln15) * 72 + ks * 32 + l4 * 8];
        oacc[nt] = __builtin_amdgcn_mfma_f32_16x16x32_bf16(ap, bv, oacc[nt], 0, 0, 0);
      }
    }
    __syncthreads();
  }
  // ---- epilogue ----
#pragma unroll
  for (int nt = 0; nt < 2; ++nt)
#pragma unroll
    for (int r = 0; r < 4; ++r) {
      const int q = q0 + w * 16 + l4 * 4 + r;
      if (q < LQ) {
        const float val = oacc[nt][r] / l_r[r];
        Ow[((size_t)q * BB + b) * CC + h * DH + nt * 16 + ln15] = f2bf(val);
      }
    }
}

// ============================================================
// LayerNorm over C=256; one wave per row; 4 rows per block.
// ============================================================
template<int TOOUT>
__global__ __launch_bounds__(256) void ln_k(const u16* __restrict__ X,
    const void* __restrict__ g, const void* __restrict__ be,
    void* __restrict__ Yv, int rows, const int* __restrict__ flag)
{
  const int df = flag[0];
  const int lane = threadIdx.x & 63;
  const int row = blockIdx.x * 4 + (threadIdx.x >> 6);
  if (row >= rows) return;
  uint2 raw = *(const uint2*)(X + (size_t)row * CC + lane * 4);
  float vx = bflo(raw.x), vy = bfhi(raw.x), vz = bflo(raw.y), vw = bfhi(raw.y);
  float s = vx + vy + vz + vw;
#pragma unroll
  for (int o = 1; o < 64; o <<= 1) s += __shfl_xor(s, o);
  const float mean = s * 0.00390625f;
  const float dx = vx - mean, dy = vy - mean, dz = vz - mean, dw = vw - mean;
  float sq = dx*dx + dy*dy + dz*dz + dw*dw;
#pragma unroll
  for (int o = 1; o < 64; o <<= 1) sq += __shfl_xor(sq, o);
  const float rstd = rsqrtf(sq * 0.00390625f + 1e-5f);
  const float g0 = ldf1(g, lane*4+0, df), g1 = ldf1(g, lane*4+1, df);
  const float g2 = ldf1(g, lane*4+2, df), g3 = ldf1(g, lane*4+3, df);
  const float b0 = ldf1(be, lane*4+0, df), b1 = ldf1(be, lane*4+1, df);
  const float b2 = ldf1(be, lane*4+2, df), b3 = ldf1(be, lane*4+3, df);
  const float y0 = dx * rstd * g0 + b0;
  const float y1 = dy * rstd * g1 + b1;
  const float y2 = dz * rstd * g2 + b2;
  const float y3 = dw * rstd * g3 + b3;
  if (TOOUT && df) {
    float* yp = (float*)Yv + (size_t)row * CC + lane * 4;
    *(float4*)yp = make_float4(y0, y1, y2, y3);
  } else {
    u16* yp = (u16*)Yv + (size_t)row * CC + lane * 4;
    unsigned int lo = (unsigned int)f2bf(y0) | ((unsigned int)f2bf(y1) << 16);
    unsigned int hi = (unsigned int)f2bf(y2) | ((unsigned int)f2bf(y3) << 16);
    *(uint2*)yp = make_uint2(lo, hi);
  }
}

// ============================================================
__global__ __launch_bounds__(256) void uv_k(
    const void* __restrict__ refp, const void* __restrict__ intr,
    const void* __restrict__ extr, float* __restrict__ uv,
    const int* __restrict__ flag)
{
  const int df = flag[0];
  const int idx = blockIdx.x * 256 + threadIdx.x;
  if (idx >= BB * NCC * LQ) return;
  const int bc = idx / LQ;
  const int q = idx - bc * LQ;
  float R[3][3], tv[3], Kc[3][3], p[3];
#pragma unroll
  for (int i = 0; i < 3; ++i) {
#pragma unroll
    for (int j = 0; j < 3; ++j) {
      R[i][j] = ldf1(extr, bc*16 + i*4 + j, df);
      Kc[i][j] = ldf1(intr, bc*9 + i*3 + j, df);
    }
    tv[i] = ldf1(extr, bc*16 + i*4 + 3, df);
  }
#pragma unroll
  for (int j = 0; j < 3; ++j) p[j] = ldf1(refp, q*3 + j, df) - tv[j];
  float pc[3];
#pragma unroll
  for (int i = 0; i < 3; ++i) pc[i] = R[0][i]*p[0] + R[1][i]*p[1] + R[2][i]*p[2];
  float im[3];
#pragma unroll
  for (int i = 0; i < 3; ++i) im[i] = Kc[i][0]*pc[0] + Kc[i][1]*pc[1] + Kc[i][2]*pc[2];
  const float z = fmaxf(im[2], 1e-5f);
  uv[(size_t)idx*2 + 0] = im[0] / z - 0.5f;
  uv[(size_t)idx*2 + 1] = im[1] / z - 0.5f;
}

// ============================================================
__global__ __launch_bounds__(256) void samp_k(
    const void* __restrict__ feat, const float* __restrict__ uv,
    u16* __restrict__ S, const int* __restrict__ flag)
{
  const int df = flag[0];
  const int c = blockIdx.x;
  const int b = blockIdx.y;
  for (int q = threadIdx.x; q < LQ; q += 256) {
    float acc = 0.f;
#pragma unroll
    for (int cam = 0; cam < NCC; ++cam) {
      const int bc = b * NCC + cam;
      const float x = uv[((size_t)bc * LQ + q) * 2 + 0];
      const float y = uv[((size_t)bc * LQ + q) * 2 + 1];
      const float xf = floorf(x), yf = floorf(y);
      const int x0 = (int)xf, y0 = (int)yf;
      const float wx = x - xf, wy = y - yf;
      const size_t base = ((size_t)bc * CC + c) * (HFF * WFF);
      const bool vx0 = (x0 >= 0) & (x0 < WFF);
      const bool vx1 = (x0 + 1 >= 0) & (x0 + 1 < WFF);
      const bool vy0 = (y0 >= 0) & (y0 < HFF);
      const bool vy1 = (y0 + 1 >= 0) & (y0 + 1 < HFF);
      if (vy0) {
        const size_t rb = base + (size_t)y0 * WFF;
        if (vx0) acc += (1.f - wx) * (1.f - wy) * ldf1(feat, rb + x0, df);
        if (vx1) acc += wx * (1.f - wy) * ldf1(feat, rb + x0 + 1, df);
      }
      if (vy1) {
        const size_t rb = base + (size_t)(y0 + 1) * WFF;
        if (vx0) acc += (1.f - wx) * wy * ldf1(feat, rb + x0, df);
        if (vx1) acc += wx * wy * ldf1(feat, rb + x0 + 1, df);
      }
    }
    S[((size_t)q * BB + b) * CC + c] = f2bf(acc * (1.f / 6.f));
  }
}

// ============================================================
extern "C" void kernel_launch(void* const* d_in, const int* in_sizes, int n_in,
                              void* d_out, int out_size, void* d_ws, size_t ws_size,
                              hipStream_t stream) {
  (void)in_sizes; (void)n_in; (void)out_size; (void)ws_size;
  char* base = (char*)d_ws;
  int* flag = (int*)base;
  float* UV = (float*)(base + WB_UV);
  u16* WQKV = (u16*)(base + WB_WQKV);
  u16* WOP  = (u16*)(base + WB_WOP);
  u16* WSC  = (u16*)(base + WB_WSC);
  u16* WF1  = (u16*)(base + WB_WF1);
  u16* WF2  = (u16*)(base + WB_WF2);
  u16* S1 = (u16*)(base + WB_S1);
  u16* S2 = (u16*)(base + WB_S2);
  u16* S3 = (u16*)(base + WB_S3);
  u16* S4 = (u16*)(base + WB_S4);
  u16* H  = (u16*)(base + WB_H);
  u16* Y3 = (u16*)(base + WB_Y3);

  detect_k<<<1, 64, 0, stream>>>((const u16*)d_in[3], flag);

  WDesc wd;
  wd.src[0] = d_in[7];  wd.dst[0] = WQKV; wd.n[0] = 196608; wd.mode[0] = 0; wd.Kd[0] = 0;    wd.Nd[0] = 0;
  wd.src[1] = d_in[9];  wd.dst[1] = WOP;  wd.n[1] = 65536;  wd.mode[1] = 0; wd.Kd[1] = 0;    wd.Nd[1] = 0;
  wd.src[2] = d_in[13]; wd.dst[2] = WSC;  wd.n[2] = 65536;  wd.mode[2] = 0; wd.Kd[2] = 0;    wd.Nd[2] = 0;
  wd.src[3] = d_in[17]; wd.dst[3] = WF1;  wd.n[3] = 262144; wd.mode[3] = 1; wd.Kd[3] = 256;  wd.Nd[3] = 1024;
  wd.src[4] = d_in[19]; wd.dst[4] = WF2;  wd.n[4] = 262144; wd.mode[4] = 1; wd.Kd[4] = 1024; wd.Nd[4] = 256;
  cvtw_k<<<dim3(256, 5), 256, 0, stream>>>(wd, flag);

  uv_k<<<(BB * NCC * LQ + 255) / 256, 256, 0, stream>>>(d_in[3], d_in[4], d_in[5], UV, flag);

  // QKV projections
  gemm_mf<1,0,0><<<dim3(4, 79), 256, 0, stream>>>(d_in[0], WQKV,          d_in[8], 0,   nullptr, S1, MROWS, CC, CC, flag);
  gemm_mf<1,0,0><<<dim3(4, 79), 256, 0, stream>>>(d_in[1], WQKV + 65536,  d_in[8], 256, nullptr, S2, MROWS, CC, CC, flag);
  gemm_mf<1,0,0><<<dim3(4, 79), 256, 0, stream>>>(d_in[1], WQKV + 131072, d_in[8], 512, nullptr, S3, MROWS, CC, CC, flag);

  attn_mf<<<dim3(40, 16), 256, 0, stream>>>(S1, S2, S3, S4);

  // out-proj (+bevq residual) -> S1, LN1 -> S2
  gemm_mf<0,0,2><<<dim3(4, 79), 256, 0, stream>>>(S4, WOP, d_in[10], 0, d_in[0], S1, MROWS, CC, CC, flag);
  ln_k<0><<<1250, 256, 0, stream>>>(S1, d_in[11], d_in[12], S2, MROWS, flag);

  // sampling -> S3
  samp_k<<<dim3(CC, BB), 256, 0, stream>>>(d_in[2], UV, S3, flag);

  // SCA (+S2 residual) -> S4, LN2 -> S1
  gemm_mf<0,0,1><<<dim3(4, 79), 256, 0, stream>>>(S3, WSC, d_in[14], 0, S2, S4, MROWS, CC, CC, flag);
  ln_k<0><<<1250, 256, 0, stream>>>(S4, d_in[15], d_in[16], S1, MROWS, flag);

  // FFN: gelu(S1 @ W1 + b1) -> H ; H @ W2 + b2 + S1 -> Y3 ; LN3 -> out
  gemm_mf<0,1,0><<<dim3(16, 79), 256, 0, stream>>>(S1, WF1, d_in[18], 0, nullptr, H,  MROWS, DFF, CC,  flag);
  gemm_mf<0,0,1><<<dim3(4, 79),  256, 0, stream>>>(H,  WF2, d_in[20], 0, S1,      Y3, MROWS, CC, DFF, flag);
  ln_k<1><<<1250, 256, 0, stream>>>(Y3, d_in[21], d_in[22], d_out, MROWS, flag);
}